// Round 3
// baseline (1002.632 us; speedup 1.0000x reference)
//
#include <hip/hip_runtime.h>

#define T_TOK 8192
#define H_DIM 2048
#define I_DIM 1408
#define N_EXP 8
#define MAX_T2 72       // 256-row tiles: sum ceil(n_e/256) <= 72
#define R_BLOCKS 512    // router blocks: 16 tokens each

#define G1_GRID (MAX_T2 * 11)   // 792 = 8*99
#define G2_GRID (MAX_T2 * 8)    // 576 = 8*72

typedef __attribute__((ext_vector_type(8))) short short8;
typedef __attribute__((ext_vector_type(8))) unsigned short ushort8;
typedef __attribute__((ext_vector_type(4))) float f32x4;

// ---- workspace layout (bytes) ----
// 32       cursor[8]
// 64       ntiles[1]
// 128      tile_e[72]
// 1280     tile_b[72]
// 2432     tile_r[72]
// 4096     topk_e[T*2]
// 69632    topk_p[T*2]
// 135168   pair_tok[16384]
// 200704   slot[16384]            (first 16KB doubles as counts_blk[512][8])
// 266240   Xb   bf16 [T][H]        33,554,432
// 33820672 G    bf16 [16384][I]    46,137,344
// 79958016 W1   bf16 [E][2816][H]  92,274,688  (gate/up 16-row interleave)
//                 then Y bf16 [16384][H] (67,108,864) overlays (dead after gemm1)
// 172232704 Wdt bf16 [E][H][I]     46,137,344

__device__ __forceinline__ unsigned short f2bf(float f) {
  unsigned u = __float_as_uint(f);
  u += 0x7fffu + ((u >> 16) & 1u);   // RNE
  return (unsigned short)(u >> 16);
}
__device__ __forceinline__ float bf2f(unsigned short u) {
  return __uint_as_float(((unsigned)u) << 16);
}

__device__ __forceinline__ void g2lds16(const unsigned short* g, unsigned short* l) {
  __builtin_amdgcn_global_load_lds(
      (const __attribute__((address_space(1))) void*)g,
      (__attribute__((address_space(3))) void*)l, 16, 0, 0);
}

// ---------------- router (+ fused X->bf16 convert) ----------------
__global__ __launch_bounds__(256) void router_kernel(
    const float* __restrict__ X, const float* __restrict__ GW,
    int* __restrict__ topk_e, float* __restrict__ topk_p,
    int* __restrict__ counts_blk, unsigned short* __restrict__ Xb) {
  int wave = threadIdx.x >> 6, lane = threadIdx.x & 63;
  __shared__ int hist[8];
  if (threadIdx.x < 8) hist[threadIdx.x] = 0;
  __syncthreads();

  int tok0 = blockIdx.x * 16 + wave * 4;
  const float4* g4 = (const float4*)GW;
  const float4* x4 = (const float4*)X;

  float acc[4][8];
#pragma unroll
  for (int t = 0; t < 4; t++)
#pragma unroll
    for (int e = 0; e < 8; e++) acc[t][e] = 0.f;

#pragma unroll
  for (int i = 0; i < 8; i++) {
    float4 gv[8];
#pragma unroll
    for (int e = 0; e < 8; e++) gv[e] = g4[e * 512 + lane + i * 64];
#pragma unroll
    for (int t = 0; t < 4; t++) {
      float4 xv = x4[(size_t)(tok0 + t) * 512 + lane + i * 64];
      ushort4 o;
      o.x = f2bf(xv.x); o.y = f2bf(xv.y); o.z = f2bf(xv.z); o.w = f2bf(xv.w);
      *(ushort4*)(Xb + (size_t)(tok0 + t) * H_DIM + (size_t)(lane + i * 64) * 4) = o;
#pragma unroll
      for (int e = 0; e < 8; e++)
        acc[t][e] += xv.x * gv[e].x + xv.y * gv[e].y + xv.z * gv[e].z + xv.w * gv[e].w;
    }
  }

#pragma unroll
  for (int t = 0; t < 4; t++) {
#pragma unroll
    for (int e = 0; e < 8; e++) {
      float v = acc[t][e];
      for (int off = 32; off; off >>= 1) v += __shfl_down(v, off);
      acc[t][e] = v;
    }
    if (lane == 0) {
      int token = tok0 + t;
      int e1 = 0; float l1 = acc[t][0];
#pragma unroll
      for (int e = 1; e < 8; e++) if (acc[t][e] > l1) { l1 = acc[t][e]; e1 = e; }
      int e2 = -1; float l2 = -1e30f;
#pragma unroll
      for (int e = 0; e < 8; e++) if (e != e1 && acc[t][e] > l2) { l2 = acc[t][e]; e2 = e; }
      float tt = __expf(l2 - l1);
      float p1 = 1.f / (1.f + tt);
      float p2 = tt / (1.f + tt);
      topk_e[token * 2] = e1; topk_e[token * 2 + 1] = e2;
      topk_p[token * 2] = p1; topk_p[token * 2 + 1] = p2;
      atomicAdd(&hist[e1], 1);
      atomicAdd(&hist[e2], 1);
    }
  }
  __syncthreads();
  if (threadIdx.x < 8) counts_blk[blockIdx.x * 8 + threadIdx.x] = hist[threadIdx.x];
}

// ---------------- setup: reduce per-block counts, offsets + 256-row tile table ----------------
__global__ __launch_bounds__(256) void setup_kernel(
    const int* __restrict__ counts_blk, int* __restrict__ cursor,
    int* __restrict__ ntiles, int* __restrict__ tile_e,
    int* __restrict__ tile_b, int* __restrict__ tile_r) {
  __shared__ int scnt[8];
  __shared__ int off[9], tb[9], cnt[8];
  int t = threadIdx.x, lane = t & 63;
  if (t < 8) scnt[t] = 0;
  __syncthreads();

  int priv[8];
#pragma unroll
  for (int e = 0; e < 8; e++) priv[e] = 0;
  for (int b = t; b < R_BLOCKS; b += 256) {
#pragma unroll
    for (int e = 0; e < 8; e++) priv[e] += counts_blk[b * 8 + e];
  }
#pragma unroll
  for (int e = 0; e < 8; e++)
    for (int o = 32; o; o >>= 1) priv[e] += __shfl_down(priv[e], o);
  if (lane == 0) {
#pragma unroll
    for (int e = 0; e < 8; e++) atomicAdd(&scnt[e], priv[e]);
  }
  __syncthreads();

  if (t == 0) {
    int o = 0, nt = 0;
    for (int e = 0; e < N_EXP; e++) {
      int n = scnt[e];
      cnt[e] = n; off[e] = o; tb[e] = nt;
      cursor[e] = o;
      nt += (n + 255) >> 8;
      o += n;
    }
    off[8] = o; tb[8] = nt;
    *ntiles = nt;
  }
  __syncthreads();
  int total = tb[8];
  for (int i = t; i < total; i += 256) {
    int e = 0;
    while (i >= tb[e + 1]) e++;
    int k = i - tb[e];
    tile_e[i] = e;
    tile_b[i] = off[e] + k * 256;
    int rem = cnt[e] - k * 256;
    tile_r[i] = rem < 256 ? rem : 256;
  }
}

// ---------------- scatter pairs: LDS-aggregated cursor reservation ----------------
__global__ __launch_bounds__(256) void scatter_kernel(
    const int* __restrict__ topk_e, int* __restrict__ cursor,
    int* __restrict__ pair_tok, int* __restrict__ slot) {
  __shared__ int lcnt[8], lbase[8];
  int tid = threadIdx.x;
  if (tid < 8) lcnt[tid] = 0;
  __syncthreads();
  int tok = blockIdx.x * 256 + tid;
  int e0 = topk_e[tok * 2], e1 = topk_e[tok * 2 + 1];
  int p0 = atomicAdd(&lcnt[e0], 1);
  int p1 = atomicAdd(&lcnt[e1], 1);
  __syncthreads();
  if (tid < 8) lbase[tid] = atomicAdd(&cursor[tid], lcnt[tid]);
  __syncthreads();
  int s0 = lbase[e0] + p0, s1 = lbase[e1] + p1;
  pair_tok[s0] = tok;
  pair_tok[s1] = tok;
  slot[tok * 2] = s0;
  slot[tok * 2 + 1] = s1;
}

// ---------------- fused transpose + convert ----------------
// z in [0,16): Wg/Wu [H][I] -> W1[e][r'][H], r' = (i>>4)*32 + s*16 + (i&15)
// z in [16,24): Wd [I][H] -> Wdt[e][h][i]
__global__ __launch_bounds__(256) void transpose_cvt_all_kernel(
    const float* __restrict__ Wg, const float* __restrict__ Wu,
    const float* __restrict__ Wd, unsigned short* __restrict__ W1,
    unsigned short* __restrict__ Wdt) {
  __shared__ float S[64][65];
  int z = blockIdx.y;
  const float* in; unsigned short* outp; int C, s = 0;
  if (z < 16) {
    s = (z >> 3) & 1;
    int e = z & 7;
    in = (s ? Wu : Wg) + (size_t)e * H_DIM * I_DIM;   // [H][I]
    outp = W1 + (size_t)e * 2816 * H_DIM;
    C = I_DIM;
  } else {
    int e = z - 16;
    in = Wd + (size_t)e * H_DIM * I_DIM;              // [I][H]
    outp = Wdt + (size_t)e * H_DIM * I_DIM;
    C = H_DIM;
  }
  int nx = C >> 6;
  int c0 = (blockIdx.x % nx) * 64, r0 = (blockIdx.x / nx) * 64;
  int t = threadIdx.x;
  int li = (t & 15) * 4, lr = t >> 4;
#pragma unroll
  for (int p = 0; p < 4; p++) {
    int r = lr + p * 16;
    float4 v = *(const float4*)(in + (size_t)(r0 + r) * C + c0 + li);
    S[r][li] = v.x; S[r][li + 1] = v.y; S[r][li + 2] = v.z; S[r][li + 3] = v.w;
  }
  __syncthreads();
  int c = t >> 2, q = t & 3;
  size_t orow;
  if (z < 16) {
    int cc2 = c0 + c;
    orow = (size_t)((cc2 >> 4) * 32 + s * 16 + (cc2 & 15)) * H_DIM;
  } else {
    orow = (size_t)(c0 + c) * I_DIM;
  }
#pragma unroll
  for (int i = 0; i < 2; i++) {
    int rb = i * 32 + q * 8;
    ushort8 o;
#pragma unroll
    for (int j = 0; j < 8; j++) o[j] = f2bf(S[rb + j][c]);
    *(ushort8*)(outp + orow + r0 + rb) = o;
  }
}

// =====================================================================
// 256x256-tile pipelined GEMM template: 8 waves (2M x 4N), BK=64,
// 4 phases/K-tile, counted vmcnt(4), T2 XOR-swizzled LDS, T5 setprio.
// Staging: body(t) stages A[t+1] (ph0,ph1) and B[t+2] (ph2,ph3).
// =====================================================================

// ---------------- GEMM1: G = silu(X W1_gate) * (X W1_up), fused via W1 interleave ----------------
__global__ __launch_bounds__(512, 2) void gemm1_kernel(
    const unsigned short* __restrict__ Xb, const unsigned short* __restrict__ W1,
    const int* __restrict__ ntiles, const int* __restrict__ tile_e,
    const int* __restrict__ tile_b, const int* __restrict__ tile_r,
    const int* __restrict__ pair_tok, unsigned short* __restrict__ G) {
  int x = blockIdx.x & 7, jj0 = blockIdx.x >> 3;
  int bx = x + 8 * (jj0 / 11);
  if (bx >= *ntiles) return;
  int n0 = (jj0 % 11) * 256;                  // W1-row block (interleaved N' = 2816)
  int e = tile_e[bx], mbase = tile_b[bx], rows = tile_r[bx];

  int tid = threadIdx.x, wid = tid >> 6, lane = tid & 63;
  int cc = lane & 15, quad = lane >> 4;
  int wm = (wid >> 2) * 128, wn = (wid & 3) * 64;
  int lr = lane >> 3;
  int koff = ((lane & 7) ^ (lr & 7)) * 8;     // inverse-swizzled source k-offset

  __shared__ __align__(16) unsigned short As[2][256][64];
  __shared__ __align__(16) unsigned short Bs[2][256][64];

  const unsigned short* w1e = W1 + (size_t)e * 2816 * H_DIM;
  const unsigned short* aS[2][2];
  const unsigned short* bS[2][2];
#pragma unroll
  for (int h = 0; h < 2; ++h)
#pragma unroll
    for (int ld = 0; ld < 2; ++ld) {
      int r = h * 128 + wid * 16 + ld * 8 + lr;
      int mr = r < rows ? r : 0;
      aS[h][ld] = Xb + (size_t)pair_tok[mbase + mr] * H_DIM + koff;
      bS[h][ld] = w1e + (size_t)(n0 + r) * H_DIM + koff;
    }

  f32x4 acc[8][4];
#pragma unroll
  for (int i = 0; i < 8; ++i)
#pragma unroll
    for (int j = 0; j < 4; ++j) acc[i][j] = (f32x4)0.f;

  int rcol[2];
  rcol[0] = (quad * 8) ^ ((cc & 7) * 8);
  rcol[1] = (32 + quad * 8) ^ ((cc & 7) * 8);

  // prologue: A[0], B[0], B[1]  (12 loads; allow B[1]'s 4 to float)
#pragma unroll
  for (int h = 0; h < 2; ++h) {
    g2lds16(aS[h][0], &As[0][h * 128 + wid * 16][0]);
    g2lds16(aS[h][1], &As[0][h * 128 + wid * 16 + 8][0]);
  }
#pragma unroll
  for (int h = 0; h < 2; ++h) {
    g2lds16(bS[h][0], &Bs[0][h * 128 + wid * 16][0]);
    g2lds16(bS[h][1], &Bs[0][h * 128 + wid * 16 + 8][0]);
  }
#pragma unroll
  for (int h = 0; h < 2; ++h) {
    g2lds16(bS[h][0] + 64, &Bs[1][h * 128 + wid * 16][0]);
    g2lds16(bS[h][1] + 64, &Bs[1][h * 128 + wid * 16 + 8][0]);
  }
  asm volatile("s_waitcnt vmcnt(4)" ::: "memory");
  __builtin_amdgcn_s_barrier();

  const int NT = H_DIM / 64;   // 32
  for (int t = 0; t < NT; ++t) {
    int cb = t & 1, nb = cb ^ 1;
    int k1 = (t + 1) * 64, k2 = (t + 2) * 64;
    short8 bf[4][2];
#pragma unroll
    for (int p = 0; p < 4; ++p) {
      if (p == 0 && t + 1 < NT) {
        g2lds16(aS[0][0] + k1, &As[nb][wid * 16][0]);
        g2lds16(aS[0][1] + k1, &As[nb][wid * 16 + 8][0]);
      }
      if (p == 1 && t + 1 < NT) {
        g2lds16(aS[1][0] + k1, &As[nb][128 + wid * 16][0]);
        g2lds16(aS[1][1] + k1, &As[nb][128 + wid * 16 + 8][0]);
      }
      if (p == 2 && t + 2 < NT) {
        g2lds16(bS[0][0] + k2, &Bs[cb][wid * 16][0]);
        g2lds16(bS[0][1] + k2, &Bs[cb][wid * 16 + 8][0]);
      }
      if (p == 3 && t + 2 < NT) {
        g2lds16(bS[1][0] + k2, &Bs[cb][128 + wid * 16][0]);
        g2lds16(bS[1][1] + k2, &Bs[cb][128 + wid * 16 + 8][0]);
      }
      asm volatile("" ::: "memory");
      if (p == 0) {
#pragma unroll
        for (int nt = 0; nt < 4; ++nt)
#pragma unroll
          for (int ks = 0; ks < 2; ++ks)
            bf[nt][ks] = *(const short8*)&Bs[cb][wn + nt * 16 + cc][rcol[ks]];
      }
      short8 af[2][2];
#pragma unroll
      for (int j = 0; j < 2; ++j)
#pragma unroll
        for (int ks = 0; ks < 2; ++ks)
          af[j][ks] = *(const short8*)&As[cb][wm + (2 * p + j) * 16 + cc][rcol[ks]];
      if (p == 3) {
        if (t == NT - 2) asm volatile("s_waitcnt vmcnt(0)" ::: "memory");
        else if (t < NT - 2) asm volatile("s_waitcnt vmcnt(4)" ::: "memory");
      }
      __builtin_amdgcn_s_barrier();
      __builtin_amdgcn_s_setprio(1);
#pragma unroll
      for (int j = 0; j < 2; ++j)
#pragma unroll
        for (int nt = 0; nt < 4; ++nt)
#pragma unroll
          for (int ks = 0; ks < 2; ++ks)
            acc[2 * p + j][nt] = __builtin_amdgcn_mfma_f32_16x16x32_bf16(
                af[j][ks], bf[nt][ks], acc[2 * p + j][nt], 0, 0, 0);
      __builtin_amdgcn_s_setprio(0);
      __builtin_amdgcn_s_barrier();
    }
  }

  // epilogue: fused silu(gate)*up, interleave -> I columns
  int ibase = ((n0 + wn) >> 5) * 16 + cc;
#pragma unroll
  for (int mt = 0; mt < 8; ++mt)
#pragma unroll
    for (int r = 0; r < 4; ++r) {
      int m = wm + mt * 16 + quad * 4 + r;
      if (m < rows) {
        unsigned short* grow = G + (size_t)(mbase + m) * I_DIM + ibase;
#pragma unroll
        for (int pp = 0; pp < 2; ++pp) {
          float g = acc[mt][2 * pp][r], u = acc[mt][2 * pp + 1][r];
          float val = (g / (1.f + __expf(-g))) * u;
          grow[pp * 16] = f2bf(val);
        }
      }
    }
}

// ---------------- GEMM2: Y[pair] = G[pair] @ Wd_e ----------------
__global__ __launch_bounds__(512, 2) void gemm2_kernel(
    const unsigned short* __restrict__ G, const unsigned short* __restrict__ Wdt,
    const int* __restrict__ ntiles, const int* __restrict__ tile_e,
    const int* __restrict__ tile_b, const int* __restrict__ tile_r,
    unsigned short* __restrict__ Y) {
  int x = blockIdx.x & 7, jj0 = blockIdx.x >> 3;
  int bx = x + 8 * (jj0 >> 3);
  if (bx >= *ntiles) return;
  int n0 = (jj0 & 7) * 256;
  int e = tile_e[bx], mbase = tile_b[bx], rows = tile_r[bx];

  int tid = threadIdx.x, wid = tid >> 6, lane = tid & 63;
  int cc = lane & 15, quad = lane >> 4;
  int wm = (wid >> 2) * 128, wn = (wid & 3) * 64;
  int lr = lane >> 3;
  int koff = ((lane & 7) ^ (lr & 7)) * 8;

  __shared__ __align__(16) unsigned short As[2][256][64];
  __shared__ __align__(16) unsigned short Bs[2][256][64];

  const unsigned short* wde = Wdt + (size_t)e * H_DIM * I_DIM;
  const unsigned short* aS[2][2];
  const unsigned short* bS[2][2];
#pragma unroll
  for (int h = 0; h < 2; ++h)
#pragma unroll
    for (int ld = 0; ld < 2; ++ld) {
      int r = h * 128 + wid * 16 + ld * 8 + lr;
      int mr = r < rows ? r : 0;
      aS[h][ld] = G + (size_t)(mbase + mr) * I_DIM + koff;
      bS[h][ld] = wde + (size_t)(n0 + r) * I_DIM + koff;
    }

  f32x4 acc[8][4];
#pragma unroll
  for (int i = 0; i < 8; ++i)
#pragma unroll
    for (int j = 0; j < 4; ++j) acc[i][j] = (f32x4)0.f;

  int rcol[2];
  rcol[0] = (quad * 8) ^ ((cc & 7) * 8);
  rcol[1] = (32 + quad * 8) ^ ((cc & 7) * 8);

#pragma unroll
  for (int h = 0; h < 2; ++h) {
    g2lds16(aS[h][0], &As[0][h * 128 + wid * 16][0]);
    g2lds16(aS[h][1], &As[0][h * 128 + wid * 16 + 8][0]);
  }
#pragma unroll
  for (int h = 0; h < 2; ++h) {
    g2lds16(bS[h][0], &Bs[0][h * 128 + wid * 16][0]);
    g2lds16(bS[h][1], &Bs[0][h * 128 + wid * 16 + 8][0]);
  }
#pragma unroll
  for (int h = 0; h < 2; ++h) {
    g2lds16(bS[h][0] + 64, &Bs[1][h * 128 + wid * 16][0]);
    g2lds16(bS[h][1] + 64, &Bs[1][h * 128 + wid * 16 + 8][0]);
  }
  asm volatile("s_waitcnt vmcnt(4)" ::: "memory");
  __builtin_amdgcn_s_barrier();

  const int NT = I_DIM / 64;   // 22
  for (int t = 0; t < NT; ++t) {
    int cb = t & 1, nb = cb ^ 1;
    int k1 = (t + 1) * 64, k2 = (t + 2) * 64;
    short8 bf[4][2];
#pragma unroll
    for (int p = 0; p < 4; ++p) {
      if (p == 0 && t + 1 < NT) {
        g2lds16(aS[0][0] + k1, &As[nb][wid * 16][0]);
        g2lds16(aS[0][1] + k1, &As[nb][wid * 16 + 8][0]);
      }
      if (p == 1 && t + 1 < NT) {
        g2lds16(aS[1][0] + k1, &As[nb][128 + wid * 16][0]);
        g2lds16(aS[1][1] + k1, &As[nb][128 + wid * 16 + 8][0]);
      }
      if (p == 2 && t + 2 < NT) {
        g2lds16(bS[0][0] + k2, &Bs[cb][wid * 16][0]);
        g2lds16(bS[0][1] + k2, &Bs[cb][wid * 16 + 8][0]);
      }
      if (p == 3 && t + 2 < NT) {
        g2lds16(bS[1][0] + k2, &Bs[cb][128 + wid * 16][0]);
        g2lds16(bS[1][1] + k2, &Bs[cb][128 + wid * 16 + 8][0]);
      }
      asm volatile("" ::: "memory");
      if (p == 0) {
#pragma unroll
        for (int nt = 0; nt < 4; ++nt)
#pragma unroll
          for (int ks = 0; ks < 2; ++ks)
            bf[nt][ks] = *(const short8*)&Bs[cb][wn + nt * 16 + cc][rcol[ks]];
      }
      short8 af[2][2];
#pragma unroll
      for (int j = 0; j < 2; ++j)
#pragma unroll
        for (int ks = 0; ks < 2; ++ks)
          af[j][ks] = *(const short8*)&As[cb][wm + (2 * p + j) * 16 + cc][rcol[ks]];
      if (p == 3) {
        if (t == NT - 2) asm volatile("s_waitcnt vmcnt(0)" ::: "memory");
        else if (t < NT - 2) asm volatile("s_waitcnt vmcnt(4)" ::: "memory");
      }
      __builtin_amdgcn_s_barrier();
      __builtin_amdgcn_s_setprio(1);
#pragma unroll
      for (int j = 0; j < 2; ++j)
#pragma unroll
        for (int nt = 0; nt < 4; ++nt)
#pragma unroll
          for (int ks = 0; ks < 2; ++ks)
            acc[2 * p + j][nt] = __builtin_amdgcn_mfma_f32_16x16x32_bf16(
                af[j][ks], bf[nt][ks], acc[2 * p + j][nt], 0, 0, 0);
      __builtin_amdgcn_s_setprio(0);
      __builtin_amdgcn_s_barrier();
    }
  }

#pragma unroll
  for (int mt = 0; mt < 8; ++mt)
#pragma unroll
    for (int r = 0; r < 4; ++r) {
      int m = wm + mt * 16 + quad * 4 + r;
      if (m < rows) {
        unsigned short* yrow = Y + (size_t)(mbase + m) * H_DIM + n0 + wn;
#pragma unroll
        for (int nt = 0; nt < 4; ++nt) yrow[nt * 16 + cc] = f2bf(acc[mt][nt][r]);
      }
    }
}

// ---------------- combine: out[t] = p1*Y[s1] + p2*Y[s2] ----------------
__global__ __launch_bounds__(256) void combine_kernel(
    const unsigned short* __restrict__ Y, const int* __restrict__ slot,
    const float* __restrict__ topk_p, float* __restrict__ out) {
  int t = blockIdx.x;
  int h = threadIdx.x * 8;
  int s1 = slot[t * 2], s2 = slot[t * 2 + 1];
  float p1 = topk_p[t * 2], p2 = topk_p[t * 2 + 1];
  ushort8 a = *(const ushort8*)(Y + (size_t)s1 * H_DIM + h);
  ushort8 b = *(const ushort8*)(Y + (size_t)s2 * H_DIM + h);
  float* o = out + (size_t)t * H_DIM + h;
  float4 o0, o1;
  o0.x = p1 * bf2f(a[0]) + p2 * bf2f(b[0]);
  o0.y = p1 * bf2f(a[1]) + p2 * bf2f(b[1]);
  o0.z = p1 * bf2f(a[2]) + p2 * bf2f(b[2]);
  o0.w = p1 * bf2f(a[3]) + p2 * bf2f(b[3]);
  o1.x = p1 * bf2f(a[4]) + p2 * bf2f(b[4]);
  o1.y = p1 * bf2f(a[5]) + p2 * bf2f(b[5]);
  o1.z = p1 * bf2f(a[6]) + p2 * bf2f(b[6]);
  o1.w = p1 * bf2f(a[7]) + p2 * bf2f(b[7]);
  *(float4*)o = o0;
  *(float4*)(o + 4) = o1;
}

extern "C" void kernel_launch(void* const* d_in, const int* in_sizes, int n_in,
                              void* d_out, int out_size, void* d_ws, size_t ws_size,
                              hipStream_t stream) {
  const float* X  = (const float*)d_in[0];
  const float* GW = (const float*)d_in[1];
  const float* Wg = (const float*)d_in[2];
  const float* Wu = (const float*)d_in[3];
  const float* Wd = (const float*)d_in[4];
  float* out = (float*)d_out;

  char* ws = (char*)d_ws;
  int*   cursor   = (int*)(ws + 32);
  int*   ntiles   = (int*)(ws + 64);
  int*   tile_e   = (int*)(ws + 128);
  int*   tile_b   = (int*)(ws + 1280);
  int*   tile_r   = (int*)(ws + 2432);
  int*   topk_e   = (int*)(ws + 4096);
  float* topk_p   = (float*)(ws + 69632);
  int*   pair_tok = (int*)(ws + 135168);
  int*   slot     = (int*)(ws + 200704);
  int*   counts_blk = (int*)(ws + 200704);  // aliases slot (stream-ordered reuse)
  unsigned short* Xb  = (unsigned short*)(ws + 266240);
  unsigned short* G   = (unsigned short*)(ws + 33820672);
  unsigned short* W1  = (unsigned short*)(ws + 79958016);
  unsigned short* Wdt = (unsigned short*)(ws + 172232704);
  unsigned short* Y   = (unsigned short*)(ws + 79958016);  // overlays W1 (dead after gemm1)

  router_kernel<<<R_BLOCKS, 256, 0, stream>>>(X, GW, topk_e, topk_p, counts_blk, Xb);
  setup_kernel<<<1, 256, 0, stream>>>(counts_blk, cursor, ntiles, tile_e, tile_b, tile_r);
  scatter_kernel<<<T_TOK / 256, 256, 0, stream>>>(topk_e, cursor, pair_tok, slot);
  transpose_cvt_all_kernel<<<dim3(704, 24), 256, 0, stream>>>(Wg, Wu, Wd, W1, Wdt);

  gemm1_kernel<<<G1_GRID, 512, 0, stream>>>(
      Xb, W1, ntiles, tile_e, tile_b, tile_r, pair_tok, G);
  gemm2_kernel<<<G2_GRID, 512, 0, stream>>>(
      G, Wdt, ntiles, tile_e, tile_b, tile_r, Y);
  combine_kernel<<<T_TOK, 256, 0, stream>>>(Y, slot, topk_p, out);
}

// Round 4
// 731.019 us; speedup vs baseline: 1.3716x; 1.3716x over previous
//
#include <hip/hip_runtime.h>

#define T_TOK 8192
#define H_DIM 2048
#define I_DIM 1408
#define N_EXP 8
#define MAX_TILES 144   // 128-row tiles: sum ceil(n_e/128) <= 136
#define R_BLOCKS 512    // router blocks: 16 tokens each

#define G1_GRID (11 * MAX_TILES)   // 1584 = 8*198; j = bid>>3 in [0,198), 198 = 11*18

typedef __attribute__((ext_vector_type(8))) short short8;
typedef __attribute__((ext_vector_type(8))) unsigned short ushort8;
typedef __attribute__((ext_vector_type(4))) float f32x4;

// ---- workspace layout (bytes) ----
// 32       cursor[8]
// 64       ntiles[1]
// 128      tile_e[144]
// 1280     tile_b[144]
// 2432     tile_r[144]
// 4096     topk_e[T*2]
// 69632    topk_p[T*2]
// 135168   pair_tok[16384]
// 200704   slot[16384]            (first 16KB doubles as counts_blk[512][8])
// 266240   Xb   bf16 [T][H]        33,554,432
// 33820672 G    bf16 [16384][I]    46,137,344
// 79958016 Wgt  bf16 [E][I][H]     46,137,344   } gemm1 inputs, then Y bf16 [16384][H] overlays
// 126095360 Wut bf16 [E][I][H]     46,137,344
// 172232704 Wdt bf16 [E][H][I]     46,137,344

__device__ __forceinline__ unsigned short f2bf(float f) {
  unsigned u = __float_as_uint(f);
  u += 0x7fffu + ((u >> 16) & 1u);   // RNE
  return (unsigned short)(u >> 16);
}
__device__ __forceinline__ float bf2f(unsigned short u) {
  return __uint_as_float(((unsigned)u) << 16);
}

__device__ __forceinline__ void g2lds16(const unsigned short* g, unsigned short* l) {
  __builtin_amdgcn_global_load_lds(
      (const __attribute__((address_space(1))) void*)g,
      (__attribute__((address_space(3))) void*)l, 16, 0, 0);
}

// ---------------- router (+ fused X->bf16 convert) ----------------
__global__ __launch_bounds__(256) void router_kernel(
    const float* __restrict__ X, const float* __restrict__ GW,
    int* __restrict__ topk_e, float* __restrict__ topk_p,
    int* __restrict__ counts_blk, unsigned short* __restrict__ Xb) {
  int wave = threadIdx.x >> 6, lane = threadIdx.x & 63;
  __shared__ int hist[8];
  if (threadIdx.x < 8) hist[threadIdx.x] = 0;
  __syncthreads();

  int tok0 = blockIdx.x * 16 + wave * 4;
  const float4* g4 = (const float4*)GW;
  const float4* x4 = (const float4*)X;

  float acc[4][8];
#pragma unroll
  for (int t = 0; t < 4; t++)
#pragma unroll
    for (int e = 0; e < 8; e++) acc[t][e] = 0.f;

#pragma unroll
  for (int i = 0; i < 8; i++) {
    float4 gv[8];
#pragma unroll
    for (int e = 0; e < 8; e++) gv[e] = g4[e * 512 + lane + i * 64];
#pragma unroll
    for (int t = 0; t < 4; t++) {
      float4 xv = x4[(size_t)(tok0 + t) * 512 + lane + i * 64];
      ushort4 o;
      o.x = f2bf(xv.x); o.y = f2bf(xv.y); o.z = f2bf(xv.z); o.w = f2bf(xv.w);
      *(ushort4*)(Xb + (size_t)(tok0 + t) * H_DIM + (size_t)(lane + i * 64) * 4) = o;
#pragma unroll
      for (int e = 0; e < 8; e++)
        acc[t][e] += xv.x * gv[e].x + xv.y * gv[e].y + xv.z * gv[e].z + xv.w * gv[e].w;
    }
  }

#pragma unroll
  for (int t = 0; t < 4; t++) {
#pragma unroll
    for (int e = 0; e < 8; e++) {
      float v = acc[t][e];
      for (int off = 32; off; off >>= 1) v += __shfl_down(v, off);
      acc[t][e] = v;
    }
    if (lane == 0) {
      int token = tok0 + t;
      int e1 = 0; float l1 = acc[t][0];
#pragma unroll
      for (int e = 1; e < 8; e++) if (acc[t][e] > l1) { l1 = acc[t][e]; e1 = e; }
      int e2 = -1; float l2 = -1e30f;
#pragma unroll
      for (int e = 0; e < 8; e++) if (e != e1 && acc[t][e] > l2) { l2 = acc[t][e]; e2 = e; }
      float tt = __expf(l2 - l1);
      float p1 = 1.f / (1.f + tt);
      float p2 = tt / (1.f + tt);
      topk_e[token * 2] = e1; topk_e[token * 2 + 1] = e2;
      topk_p[token * 2] = p1; topk_p[token * 2 + 1] = p2;
      atomicAdd(&hist[e1], 1);
      atomicAdd(&hist[e2], 1);
    }
  }
  __syncthreads();
  if (threadIdx.x < 8) counts_blk[blockIdx.x * 8 + threadIdx.x] = hist[threadIdx.x];
}

// ---------------- setup: reduce per-block counts, offsets + 128-row tile table ----------------
__global__ __launch_bounds__(256) void setup_kernel(
    const int* __restrict__ counts_blk, int* __restrict__ cursor,
    int* __restrict__ ntiles, int* __restrict__ tile_e,
    int* __restrict__ tile_b, int* __restrict__ tile_r) {
  __shared__ int scnt[8];
  __shared__ int off[9], tb[9], cnt[8];
  int t = threadIdx.x, lane = t & 63;
  if (t < 8) scnt[t] = 0;
  __syncthreads();

  int priv[8];
#pragma unroll
  for (int e = 0; e < 8; e++) priv[e] = 0;
  for (int b = t; b < R_BLOCKS; b += 256) {
#pragma unroll
    for (int e = 0; e < 8; e++) priv[e] += counts_blk[b * 8 + e];
  }
#pragma unroll
  for (int e = 0; e < 8; e++)
    for (int o = 32; o; o >>= 1) priv[e] += __shfl_down(priv[e], o);
  if (lane == 0) {
#pragma unroll
    for (int e = 0; e < 8; e++) atomicAdd(&scnt[e], priv[e]);
  }
  __syncthreads();

  if (t == 0) {
    int o = 0, nt = 0;
    for (int e = 0; e < N_EXP; e++) {
      int n = scnt[e];
      cnt[e] = n; off[e] = o; tb[e] = nt;
      cursor[e] = o;
      nt += (n + 127) >> 7;
      o += n;
    }
    off[8] = o; tb[8] = nt;
    *ntiles = nt;
  }
  __syncthreads();
  int total = tb[8];
  for (int i = t; i < total; i += 256) {
    int e = 0;
    while (i >= tb[e + 1]) e++;
    int k = i - tb[e];
    tile_e[i] = e;
    tile_b[i] = off[e] + k * 128;
    int rem = cnt[e] - k * 128;
    tile_r[i] = rem < 128 ? rem : 128;
  }
}

// ---------------- scatter pairs: LDS-aggregated cursor reservation ----------------
__global__ __launch_bounds__(256) void scatter_kernel(
    const int* __restrict__ topk_e, int* __restrict__ cursor,
    int* __restrict__ pair_tok, int* __restrict__ slot) {
  __shared__ int lcnt[8], lbase[8];
  int tid = threadIdx.x;
  if (tid < 8) lcnt[tid] = 0;
  __syncthreads();
  int tok = blockIdx.x * 256 + tid;
  int e0 = topk_e[tok * 2], e1 = topk_e[tok * 2 + 1];
  int p0 = atomicAdd(&lcnt[e0], 1);
  int p1 = atomicAdd(&lcnt[e1], 1);
  __syncthreads();
  if (tid < 8) lbase[tid] = atomicAdd(&cursor[tid], lcnt[tid]);
  __syncthreads();
  int s0 = lbase[e0] + p0, s1 = lbase[e1] + p1;
  pair_tok[s0] = tok;
  pair_tok[s1] = tok;
  slot[tok * 2] = s0;
  slot[tok * 2 + 1] = s1;
}

// ---------------- fused transpose + convert for all 3 weight tensors ----------------
// z in [0,8): Wg->Wgt  [8,16): Wu->Wut  [16,24): Wd->Wdt (R/C swapped)
__global__ __launch_bounds__(256) void transpose_cvt_all_kernel(
    const float* __restrict__ Wg, const float* __restrict__ Wu,
    const float* __restrict__ Wd, unsigned short* __restrict__ Wgt,
    unsigned short* __restrict__ Wut, unsigned short* __restrict__ Wdt) {
  __shared__ float S[64][65];
  int z = blockIdx.y;
  const float* in; unsigned short* out; int R, C, e;
  if (z < 8)       { in = Wg; out = Wgt; R = H_DIM; C = I_DIM; e = z; }
  else if (z < 16) { in = Wu; out = Wut; R = H_DIM; C = I_DIM; e = z - 8; }
  else             { in = Wd; out = Wdt; R = I_DIM; C = H_DIM; e = z - 16; }
  int nx = C >> 6;
  int bid = blockIdx.x;
  int c0 = (bid % nx) * 64, r0 = (bid / nx) * 64;
  const float* ine = in + (size_t)e * H_DIM * I_DIM;
  unsigned short* oute = out + (size_t)e * H_DIM * I_DIM;
  int t = threadIdx.x;
  int li = (t & 15) * 4, lr = t >> 4;
#pragma unroll
  for (int p = 0; p < 4; p++) {
    int r = lr + p * 16;
    float4 v = *(const float4*)(ine + (size_t)(r0 + r) * C + c0 + li);
    S[r][li] = v.x; S[r][li + 1] = v.y; S[r][li + 2] = v.z; S[r][li + 3] = v.w;
  }
  __syncthreads();
  int c = t >> 2, q = t & 3;
#pragma unroll
  for (int i = 0; i < 2; i++) {
    int rb = i * 32 + q * 8;
    ushort8 o;
#pragma unroll
    for (int j = 0; j < 8; j++) o[j] = f2bf(S[rb + j][c]);
    *(ushort8*)(oute + (size_t)(c0 + c) * R + r0 + rb) = o;
  }
}

// ---------------- GEMM1: G = silu(X Wg) * (X Wu) — 128x128, K=64 per barrier ----------------
// Balanced round-robin tile->XCD map: x = bid&7 (XCD), tile = x + 8*(j/11).
// All 11 n-blocks of a tile on one XCD (A-panel fetched into one L2); empty
// tiles (bx >= ntiles) spread evenly mod 8; same-expert tile pairs (mod 8)
// retain B-panel L2 reuse.
__global__ __launch_bounds__(256, 2) void gemm1_kernel(
    const unsigned short* __restrict__ Xb, const unsigned short* __restrict__ Wgt,
    const unsigned short* __restrict__ Wut, const int* __restrict__ ntiles,
    const int* __restrict__ tile_e, const int* __restrict__ tile_b,
    const int* __restrict__ tile_r, const int* __restrict__ pair_tok,
    unsigned short* __restrict__ G) {
  int orig = blockIdx.x;
  int x = orig & 7, j = orig >> 3;        // j in [0,198)
  int bx = x + 8 * (j / 11);
  if (bx >= *ntiles) return;
  int n0 = (j % 11) * 128;
  int e = tile_e[bx], mbase = tile_b[bx], rows = tile_r[bx];
  int tid = threadIdx.x, wave = tid >> 6, lane = tid & 63;
  int quad = lane >> 4, c = lane & 15;
  int wm = (wave & 1) * 64, wn = (wave >> 1) * 64;

  __shared__ __align__(16) unsigned short As[2][128][32];
  __shared__ __align__(16) unsigned short Bgs[2][128][32];
  __shared__ __align__(16) unsigned short Bus[2][128][32];

  int srow = wave * 32 + (lane >> 2);
  int selem = (lane & 3) * 8;
  int mr0 = srow < rows ? srow : 0;
  int mr1 = (srow + 16) < rows ? (srow + 16) : 0;
  const unsigned short* gA0 = Xb + (size_t)pair_tok[mbase + mr0] * H_DIM + selem;
  const unsigned short* gA1 = Xb + (size_t)pair_tok[mbase + mr1] * H_DIM + selem;
  const unsigned short* bg = Wgt + (size_t)e * H_DIM * I_DIM;
  const unsigned short* bu = Wut + (size_t)e * H_DIM * I_DIM;
  const unsigned short* gG0 = bg + (size_t)(n0 + srow) * H_DIM + selem;
  const unsigned short* gG1 = bg + (size_t)(n0 + srow + 16) * H_DIM + selem;
  const unsigned short* gU0 = bu + (size_t)(n0 + srow) * H_DIM + selem;
  const unsigned short* gU1 = bu + (size_t)(n0 + srow + 16) * H_DIM + selem;

  f32x4 accg[4][4], accu[4][4];
#pragma unroll
  for (int i = 0; i < 4; i++)
#pragma unroll
    for (int jj = 0; jj < 4; jj++) { accg[i][jj] = (f32x4)0.f; accu[i][jj] = (f32x4)0.f; }

  for (int k0 = 0; k0 < H_DIM; k0 += 64) {
    __syncthreads();
#pragma unroll
    for (int s = 0; s < 2; s++) {
      int kk = k0 + s * 32;
      g2lds16(gA0 + kk, &As[s][wave * 32][0]);
      g2lds16(gA1 + kk, &As[s][wave * 32 + 16][0]);
      g2lds16(gG0 + kk, &Bgs[s][wave * 32][0]);
      g2lds16(gG1 + kk, &Bgs[s][wave * 32 + 16][0]);
      g2lds16(gU0 + kk, &Bus[s][wave * 32][0]);
      g2lds16(gU1 + kk, &Bus[s][wave * 32 + 16][0]);
    }
    __syncthreads();

#pragma unroll
    for (int h = 0; h < 2; h++) {
      short8 af[4], bgf[4], buf[4];
#pragma unroll
      for (int mt = 0; mt < 4; mt++)
        af[mt] = *(const short8*)&As[h][wm + mt * 16 + c][quad * 8];
#pragma unroll
      for (int nt = 0; nt < 4; nt++) {
        bgf[nt] = *(const short8*)&Bgs[h][wn + nt * 16 + c][quad * 8];
        buf[nt] = *(const short8*)&Bus[h][wn + nt * 16 + c][quad * 8];
      }
#pragma unroll
      for (int mt = 0; mt < 4; mt++)
#pragma unroll
        for (int nt = 0; nt < 4; nt++) {
          accg[mt][nt] = __builtin_amdgcn_mfma_f32_16x16x32_bf16(af[mt], bgf[nt], accg[mt][nt], 0, 0, 0);
          accu[mt][nt] = __builtin_amdgcn_mfma_f32_16x16x32_bf16(af[mt], buf[nt], accu[mt][nt], 0, 0, 0);
        }
    }
  }

#pragma unroll
  for (int mt = 0; mt < 4; mt++)
#pragma unroll
    for (int r = 0; r < 4; r++) {
      int m = wm + mt * 16 + quad * 4 + r;
      if (m < rows) {
        unsigned short* grow = G + (size_t)(mbase + m) * I_DIM + n0 + wn;
#pragma unroll
        for (int nt = 0; nt < 4; nt++) {
          float g = accg[mt][nt][r], u = accu[mt][nt][r];
          float val = (g / (1.f + __expf(-g))) * u;
          grow[nt * 16 + c] = f2bf(val);
        }
      }
    }
}

// ---------------- GEMM2: Y[pair] = G[pair] @ Wd_e — plain grid (16, tiles), proven R1 form ----------------
__global__ __launch_bounds__(256, 3) void gemm2_kernel(
    const unsigned short* __restrict__ G, const unsigned short* __restrict__ Wdt,
    const int* __restrict__ ntiles, const int* __restrict__ tile_e,
    const int* __restrict__ tile_b, const int* __restrict__ tile_r,
    unsigned short* __restrict__ Y) {
  int bx = blockIdx.y;
  if (bx >= *ntiles) return;
  int e = tile_e[bx], mbase = tile_b[bx], rows = tile_r[bx];
  int n0 = blockIdx.x * 128;
  int tid = threadIdx.x, wave = tid >> 6, lane = tid & 63;
  int quad = lane >> 4, c = lane & 15;
  int wm = (wave & 1) * 64, wn = (wave >> 1) * 64;

  __shared__ __align__(16) unsigned short As[2][128][32];
  __shared__ __align__(16) unsigned short Bs[2][128][32];

  int srow = wave * 32 + (lane >> 2);
  int selem = (lane & 3) * 8;
  int mr0 = srow < rows ? srow : 0;
  int mr1 = (srow + 16) < rows ? (srow + 16) : 0;
  const unsigned short* gA0 = G + (size_t)(mbase + mr0) * I_DIM + selem;
  const unsigned short* gA1 = G + (size_t)(mbase + mr1) * I_DIM + selem;
  const unsigned short* bd = Wdt + (size_t)e * H_DIM * I_DIM;
  const unsigned short* gB0 = bd + (size_t)(n0 + srow) * I_DIM + selem;
  const unsigned short* gB1 = bd + (size_t)(n0 + srow + 16) * I_DIM + selem;

  f32x4 acc[4][4];
#pragma unroll
  for (int i = 0; i < 4; i++)
#pragma unroll
    for (int jj = 0; jj < 4; jj++) acc[i][jj] = (f32x4)0.f;

  for (int k0 = 0; k0 < I_DIM; k0 += 64) {
    __syncthreads();
#pragma unroll
    for (int s = 0; s < 2; s++) {
      int kk = k0 + s * 32;
      g2lds16(gA0 + kk, &As[s][wave * 32][0]);
      g2lds16(gA1 + kk, &As[s][wave * 32 + 16][0]);
      g2lds16(gB0 + kk, &Bs[s][wave * 32][0]);
      g2lds16(gB1 + kk, &Bs[s][wave * 32 + 16][0]);
    }
    __syncthreads();

#pragma unroll
    for (int h = 0; h < 2; h++) {
      short8 af[4], bf[4];
#pragma unroll
      for (int mt = 0; mt < 4; mt++)
        af[mt] = *(const short8*)&As[h][wm + mt * 16 + c][quad * 8];
#pragma unroll
      for (int nt = 0; nt < 4; nt++)
        bf[nt] = *(const short8*)&Bs[h][wn + nt * 16 + c][quad * 8];
#pragma unroll
      for (int mt = 0; mt < 4; mt++)
#pragma unroll
        for (int nt = 0; nt < 4; nt++)
          acc[mt][nt] = __builtin_amdgcn_mfma_f32_16x16x32_bf16(af[mt], bf[nt], acc[mt][nt], 0, 0, 0);
    }
  }

#pragma unroll
  for (int mt = 0; mt < 4; mt++)
#pragma unroll
    for (int r = 0; r < 4; r++) {
      int m = wm + mt * 16 + quad * 4 + r;
      if (m < rows) {
        unsigned short* yrow = Y + (size_t)(mbase + m) * H_DIM + n0 + wn;
#pragma unroll
        for (int nt = 0; nt < 4; nt++) yrow[nt * 16 + c] = f2bf(acc[mt][nt][r]);
      }
    }
}

// ---------------- combine: out[t] = p1*Y[s1] + p2*Y[s2] ----------------
__global__ __launch_bounds__(256) void combine_kernel(
    const unsigned short* __restrict__ Y, const int* __restrict__ slot,
    const float* __restrict__ topk_p, float* __restrict__ out) {
  int t = blockIdx.x;
  int h = threadIdx.x * 8;
  int s1 = slot[t * 2], s2 = slot[t * 2 + 1];
  float p1 = topk_p[t * 2], p2 = topk_p[t * 2 + 1];
  ushort8 a = *(const ushort8*)(Y + (size_t)s1 * H_DIM + h);
  ushort8 b = *(const ushort8*)(Y + (size_t)s2 * H_DIM + h);
  float* o = out + (size_t)t * H_DIM + h;
  float4 o0, o1;
  o0.x = p1 * bf2f(a[0]) + p2 * bf2f(b[0]);
  o0.y = p1 * bf2f(a[1]) + p2 * bf2f(b[1]);
  o0.z = p1 * bf2f(a[2]) + p2 * bf2f(b[2]);
  o0.w = p1 * bf2f(a[3]) + p2 * bf2f(b[3]);
  o1.x = p1 * bf2f(a[4]) + p2 * bf2f(b[4]);
  o1.y = p1 * bf2f(a[5]) + p2 * bf2f(b[5]);
  o1.z = p1 * bf2f(a[6]) + p2 * bf2f(b[6]);
  o1.w = p1 * bf2f(a[7]) + p2 * bf2f(b[7]);
  *(float4*)o = o0;
  *(float4*)(o + 4) = o1;
}

extern "C" void kernel_launch(void* const* d_in, const int* in_sizes, int n_in,
                              void* d_out, int out_size, void* d_ws, size_t ws_size,
                              hipStream_t stream) {
  const float* X  = (const float*)d_in[0];
  const float* GW = (const float*)d_in[1];
  const float* Wg = (const float*)d_in[2];
  const float* Wu = (const float*)d_in[3];
  const float* Wd = (const float*)d_in[4];
  float* out = (float*)d_out;

  char* ws = (char*)d_ws;
  int*   cursor   = (int*)(ws + 32);
  int*   ntiles   = (int*)(ws + 64);
  int*   tile_e   = (int*)(ws + 128);
  int*   tile_b   = (int*)(ws + 1280);
  int*   tile_r   = (int*)(ws + 2432);
  int*   topk_e   = (int*)(ws + 4096);
  float* topk_p   = (float*)(ws + 69632);
  int*   pair_tok = (int*)(ws + 135168);
  int*   slot     = (int*)(ws + 200704);
  int*   counts_blk = (int*)(ws + 200704);  // aliases slot (stream-ordered reuse)
  unsigned short* Xb  = (unsigned short*)(ws + 266240);
  unsigned short* G   = (unsigned short*)(ws + 33820672);
  unsigned short* Wgt = (unsigned short*)(ws + 79958016);
  unsigned short* Wut = (unsigned short*)(ws + 126095360);
  unsigned short* Wdt = (unsigned short*)(ws + 172232704);
  unsigned short* Y   = (unsigned short*)(ws + 79958016);  // overlays Wgt/Wut (dead after gemm1)

  router_kernel<<<R_BLOCKS, 256, 0, stream>>>(X, GW, topk_e, topk_p, counts_blk, Xb);
  setup_kernel<<<1, 256, 0, stream>>>(counts_blk, cursor, ntiles, tile_e, tile_b, tile_r);
  scatter_kernel<<<T_TOK / 256, 256, 0, stream>>>(topk_e, cursor, pair_tok, slot);
  transpose_cvt_all_kernel<<<dim3(704, 24), 256, 0, stream>>>(Wg, Wu, Wd, Wgt, Wut, Wdt);

  gemm1_kernel<<<G1_GRID, 256, 0, stream>>>(
      Xb, Wgt, Wut, ntiles, tile_e, tile_b, tile_r, pair_tok, G);
  gemm2_kernel<<<dim3(H_DIM / 128, MAX_TILES), 256, 0, stream>>>(
      G, Wdt, ntiles, tile_e, tile_b, tile_r, Y);
  combine_kernel<<<T_TOK, 256, 0, stream>>>(Y, slot, topk_p, out);
}